// Round 8
// baseline (156.598 us; speedup 1.0000x reference)
//
#include <hip/hip_runtime.h>
#include <hip/hip_bf16.h>
#include <math.h>

#define S 256
#define D 128
#define H 4
#define HD 32

constexpr float EPS = 1e-5f;
constexpr float EXPC = 0.17677669529663687f * 1.44269504088896f;  // scale*log2(e)

typedef short bf16x8 __attribute__((ext_vector_type(8)));
typedef float floatx4 __attribute__((ext_vector_type(4)));

union BfBits { __hip_bfloat16 b; unsigned short u; };
__device__ inline unsigned short f2bf_bits(float f) {
  BfBits t;
  t.b = __float2bfloat16(f);
  return t.u;
}
__device__ inline short f2bf_s(float f) { return (short)f2bf_bits(f); }
__device__ inline float bfbits2f(unsigned short u) {
  union { float f; unsigned int i; } t;
  t.i = ((unsigned int)u) << 16;
  return t.f;
}
// split x into bf16 hi + bf16 lo with x ~= hi + lo (error <= 2^-18 relative)
__device__ inline void split_bf(float x, unsigned short& hi, unsigned short& lo) {
  hi = f2bf_bits(x);
  lo = f2bf_bits(x - bfbits2f(hi));
}
__device__ inline unsigned int pk2(float a, float b) {
  return (unsigned int)f2bf_bits(a) | ((unsigned int)f2bf_bits(b) << 16);
}

// ---------------------------------------------------------------------------
// K0: split the four 128x128 fp32 weights into bf16 hi/lo pairs, original
// [d][c] layout (== MFMA A-operand row layout). Order: q, k, v, o.
// ---------------------------------------------------------------------------
__global__ __launch_bounds__(256) void wsplit_kernel(
    const float* __restrict__ wq, const float* __restrict__ wk,
    const float* __restrict__ wv, const float* __restrict__ wo,
    unsigned short* __restrict__ whi, unsigned short* __restrict__ wlo) {
  int idx = blockIdx.x * 256 + threadIdx.x;  // 0..16383
  const float* srcs[4] = {wq, wk, wv, wo};
#pragma unroll
  for (int m = 0; m < 4; m++) {
    unsigned short hi, lo;
    split_bf(srcs[m][idx], hi, lo);
    whi[m * 16384 + idx] = hi;
    wlo[m * 16384 + idx] = lo;
  }
}

// ---------------------------------------------------------------------------
// R15: R7 shell (8 waves / 512 thr / (512,2) / grid 256 — the only
// spill-free shape, ledger R1/R5/R6) + two latency cuts:
//  1. K/V weight fragments HOISTED to registers before the jt loop (64
//     VGPR; R7 re-loaded the same 16 frags from L2 every tile = 64 loads
//     x ~200cy exposure that 2 waves/SIMD can't hide). Produce is now
//     pure LDS+MFMA. Peak liveness est ~235 < 256 cap of (512,2);
//     falsifier: FETCH > 25MB = spill -> revert.
//  2. P4 O-deposit as separate hi/lo PLANES (64KB+64KB overlay, same
//     bytes) instead of hi|lo<<16 packed words: projection reads become
//     direct bf16x8 loads, killing 512 unpack-VALU-ops/wave. Same
//     rounding path -> bit-identical output.
// R7 post-mortem: predictions matched (WRITE 62->32MB, dur 85->63us);
// still latency-bound: all pipes <40% at the architectural 2 waves/SIMD
// cap (LDS 128KB = 1 block/CU; 4 waves/SIMD = 128-reg cap = spill).
// Wave roles: (h=w>>1, half=w&1). P1: LN tokens w*32..+31. P2/consume:
// head h, queries half*128..+127. Produce: head h, hd-half half*16, all 64
// j-tokens. P4: deposit own queries; project dims (w&3)*32..+31, tokens
// (w>>2)*128..+127.
// ---------------------------------------------------------------------------
#define XS(row, col) ((col) ^ (((row) & 7) << 3))

__device__ __forceinline__ floatx4 MF(bf16x8 a, bf16x8 b, floatx4 c) {
  return __builtin_amdgcn_mfma_f32_16x16x32_bf16(a, b, c, 0, 0, 0);
}

struct KVW {  // hoisted K/V weight fragments: 16 x bf16x8 = 64 VGPR
  bf16x8 kh[4], kl[4], vh[4], vl[4];
};

// produce K,V for tokens jt*64..+63, head h, hd hb..hb+15; pure LDS+MFMA
__device__ __forceinline__ void kv_produce(const unsigned short* xn,
                                           const KVW& kvw,
                                           unsigned short* base, int jt, int h,
                                           int hb, int c16, int quad) {
  unsigned short* Kt = base;
  unsigned short* Vt = base + 8192;
  floatx4 ak[4], av[4];
#pragma unroll
  for (int nt = 0; nt < 4; nt++) {
    ak[nt] = (floatx4){0.f, 0.f, 0.f, 0.f};
    av[nt] = (floatx4){0.f, 0.f, 0.f, 0.f};
  }
#pragma unroll
  for (int ks = 0; ks < 4; ks++) {
    bf16x8 bh[4];
#pragma unroll
    for (int nt = 0; nt < 4; nt++) {
      const int row = jt * 64 + nt * 16 + c16;
      bh[nt] = *(const bf16x8*)&xn[row * D + XS(row, ks * 32 + quad * 8)];
    }
#pragma unroll
    for (int nt = 0; nt < 4; nt++) {
      ak[nt] = MF(kvw.kh[ks], bh[nt], ak[nt]);
      ak[nt] = MF(kvw.kl[ks], bh[nt], ak[nt]);
      av[nt] = MF(kvw.vh[ks], bh[nt], av[nt]);
      av[nt] = MF(kvw.vl[ks], bh[nt], av[nt]);
    }
  }
  const int c2 = (hb >> 3) + (quad >> 1);
#pragma unroll
  for (int nt = 0; nt < 4; nt++) {
    const int jl = nt * 16 + c16;
    ushort4 pkk;
    pkk.x = f2bf_bits(ak[nt][0]);
    pkk.y = f2bf_bits(ak[nt][1]);
    pkk.z = f2bf_bits(ak[nt][2]);
    pkk.w = f2bf_bits(ak[nt][3]);
    *(ushort4*)(Kt + h * 2048 + c2 * 512 + jl * 8 + (quad & 1) * 4) = pkk;
#pragma unroll
    for (int r2 = 0; r2 < 4; r2++) {
      const int hd = hb + quad * 4 + r2;
      Vt[h * 2048 + hd * 64 + (((jl >> 3) ^ (hd & 7)) << 3) + (jl & 7)] =
          f2bf_bits(av[nt][r2]);
    }
  }
}

// consume one 64-token j-tile for this wave's 128 queries (head h)
__device__ __forceinline__ void attn_consume(const unsigned short* base, int h,
                                             int c16, int quad, int permc,
                                             const bf16x8 qf[8], floatx4 att0[8],
                                             floatx4 att1[8], float lsum[8]) {
  const unsigned short* Kt = base;
  const unsigned short* Vt = base + 8192;
#pragma unroll
  for (int jb = 0; jb < 2; jb++) {
    const int jbl = jb * 32;
    bf16x8 kf0 = *(const bf16x8*)(Kt + h * 2048 + quad * 512 + (jbl + permc) * 8);
    bf16x8 kf1 = *(const bf16x8*)(Kt + h * 2048 + quad * 512 + (jbl + permc + 4) * 8);
    const int ch = (jbl >> 3) + quad;
    bf16x8 vf0 = *(const bf16x8*)(Vt + h * 2048 + c16 * 64 + ((ch ^ (c16 & 7)) << 3));
    bf16x8 vf1 = *(const bf16x8*)(Vt + h * 2048 + (16 + c16) * 64 + ((ch ^ (c16 & 7)) << 3));
#pragma unroll
    for (int qt = 0; qt < 8; qt++) {
      floatx4 s0 = MF(kf0, qf[qt], (floatx4){0.f, 0.f, 0.f, 0.f});
      floatx4 s1 = MF(kf1, qf[qt], (floatx4){0.f, 0.f, 0.f, 0.f});
      float pr[8];
#pragma unroll
      for (int r = 0; r < 4; r++) pr[r] = exp2f(s0[r]);  // EXPC pre-folded in Q
#pragma unroll
      for (int r = 0; r < 4; r++) pr[4 + r] = exp2f(s1[r]);
      float ls = 0.f;
#pragma unroll
      for (int r = 0; r < 8; r++) ls += pr[r];
      lsum[qt] += ls;
      bf16x8 pf;
#pragma unroll
      for (int r = 0; r < 8; r++) pf[r] = f2bf_s(pr[r]);
      att0[qt] = MF(vf0, pf, att0[qt]);
      att1[qt] = MF(vf1, pf, att1[qt]);
    }
  }
}

__global__ __launch_bounds__(512, 2) void fused_tri_kernel(
    const float* __restrict__ pair, const float* __restrict__ ln_w,
    const unsigned short* __restrict__ Whi,
    const unsigned short* __restrict__ Wlo, float* __restrict__ out) {
  __shared__ unsigned int smem[32768];  // 128 KB
  unsigned short* xn = (unsigned short*)smem;  // [256][128] bf16, XS-swizzled

  const int i = blockIdx.x;
  const int w = (int)(threadIdx.x >> 6);  // 0..7
  const int lane = (int)(threadIdx.x & 63);
  const int c16 = lane & 15;
  const int quad = lane >> 4;
  const int h = w >> 1;     // head
  const int half = w & 1;   // query half / hd half
  const int hb = half * 16;

  // ---- P1: LayerNorm, 32 tokens/wave: prefetch ALL, then reduce ----
  {
    float4 w0 = *(const float4*)(ln_w + c16 * 8);
    float4 w1 = *(const float4*)(ln_w + c16 * 8 + 4);
    float4 xr0[8], xr1[8];
#pragma unroll
    for (int g = 0; g < 8; g++) {
      const int tok = w * 32 + g * 4 + quad;
      const float* src = pair + ((size_t)i * S + tok) * D + c16 * 8;
      xr0[g] = *(const float4*)(src);
      xr1[g] = *(const float4*)(src + 4);
    }
#pragma unroll
    for (int g = 0; g < 8; g++) {
      const int tok = w * 32 + g * 4 + quad;
      float4 x0 = xr0[g];
      float4 x1 = xr1[g];
      float s = (x0.x + x0.y) + (x0.z + x0.w) + (x1.x + x1.y) + (x1.z + x1.w);
      s += __shfl_xor(s, 1);
      s += __shfl_xor(s, 2);
      s += __shfl_xor(s, 4);
      s += __shfl_xor(s, 8);
      const float mu = s * (1.0f / D);
      float a[8];
      a[0] = x0.x - mu; a[1] = x0.y - mu; a[2] = x0.z - mu; a[3] = x0.w - mu;
      a[4] = x1.x - mu; a[5] = x1.y - mu; a[6] = x1.z - mu; a[7] = x1.w - mu;
      float vs = 0.f;
#pragma unroll
      for (int r = 0; r < 8; r++) vs = fmaf(a[r], a[r], vs);
      vs += __shfl_xor(vs, 1);
      vs += __shfl_xor(vs, 2);
      vs += __shfl_xor(vs, 4);
      vs += __shfl_xor(vs, 8);
      const float rinv = rsqrtf(vs * (1.0f / D) + EPS);
      const float wv8[8] = {w0.x, w0.y, w0.z, w0.w, w1.x, w1.y, w1.z, w1.w};
      unsigned int u[4];
#pragma unroll
      for (int r = 0; r < 4; r++) {
        unsigned int h0 = f2bf_bits(a[2 * r] * rinv * wv8[2 * r]);
        unsigned int h1 = f2bf_bits(a[2 * r + 1] * rinv * wv8[2 * r + 1]);
        u[r] = h0 | (h1 << 16);
      }
      uint4 st = {u[0], u[1], u[2], u[3]};
      *(uint4*)&xn[tok * D + XS(tok, c16 * 8)] = st;
    }
  }
  __syncthreads();

  // ---- P2: Q projection -> register fragments (128 queries/wave) ----
  bf16x8 qf[8];
  {
    bf16x8 qah[2][4], qal[2][4];
#pragma unroll
    for (int mi = 0; mi < 2; mi++)
#pragma unroll
      for (int ks = 0; ks < 4; ks++) {
        const int arow = h * 32 + mi * 16 + c16;
        qah[mi][ks] = *(const bf16x8*)(Whi + arow * D + ks * 32 + quad * 8);
        qal[mi][ks] = *(const bf16x8*)(Wlo + arow * D + ks * 32 + quad * 8);
      }
#pragma unroll
    for (int r = 0; r < 2; r++) {
      floatx4 acc[2][4];
#pragma unroll
      for (int mi = 0; mi < 2; mi++)
#pragma unroll
        for (int nt = 0; nt < 4; nt++) acc[mi][nt] = (floatx4){0.f, 0.f, 0.f, 0.f};
#pragma unroll
      for (int ks = 0; ks < 4; ks++) {
        bf16x8 bh[4];
#pragma unroll
        for (int nt = 0; nt < 4; nt++) {
          const int row = half * 128 + r * 64 + nt * 16 + c16;
          bh[nt] = *(const bf16x8*)&xn[row * D + XS(row, ks * 32 + quad * 8)];
        }
#pragma unroll
        for (int mi = 0; mi < 2; mi++)
#pragma unroll
          for (int nt = 0; nt < 4; nt++) {
            acc[mi][nt] = MF(qah[mi][ks], bh[nt], acc[mi][nt]);
            acc[mi][nt] = MF(qal[mi][ks], bh[nt], acc[mi][nt]);
          }
      }
      // quad redistribution: proj layout (4 consecutive d/lane) ->
      // attention B-fragment (8 consecutive hd/lane); EXPC folded here.
      const int srcL = c16 + (quad & 1) * 32;
      const int srcH = srcL + 16;
      const bool hi2 = quad >= 2;
#pragma unroll
      for (int nt = 0; nt < 4; nt++) {
        int pa = (int)pk2(acc[0][nt][0] * EXPC, acc[0][nt][1] * EXPC);
        int pb = (int)pk2(acc[0][nt][2] * EXPC, acc[0][nt][3] * EXPC);
        int pc = (int)pk2(acc[1][nt][0] * EXPC, acc[1][nt][1] * EXPC);
        int pd = (int)pk2(acc[1][nt][2] * EXPC, acc[1][nt][3] * EXPC);
        int aL = __shfl(pa, srcL), cL = __shfl(pc, srcL);
        int bL = __shfl(pb, srcL), dL = __shfl(pd, srcL);
        int aH = __shfl(pa, srcH), cH = __shfl(pc, srcH);
        int bH = __shfl(pb, srcH), dH = __shfl(pd, srcH);
        union { unsigned int u[4]; bf16x8 v; } qq_;
        qq_.u[0] = (unsigned int)(hi2 ? cL : aL);
        qq_.u[1] = (unsigned int)(hi2 ? dL : bL);
        qq_.u[2] = (unsigned int)(hi2 ? cH : aH);
        qq_.u[3] = (unsigned int)(hi2 ? dH : bH);
        qf[r * 4 + nt] = qq_.v;
      }
    }
  }

  // ---- hoist K/V weight fragments (reused across all 4 j-tiles) ----
  KVW kvw;
  {
    const int arow = h * 32 + hb + c16;
#pragma unroll
    for (int ks = 0; ks < 4; ks++) {
      kvw.kh[ks] = *(const bf16x8*)(Whi + 16384 + arow * D + ks * 32 + quad * 8);
      kvw.kl[ks] = *(const bf16x8*)(Wlo + 16384 + arow * D + ks * 32 + quad * 8);
      kvw.vh[ks] = *(const bf16x8*)(Whi + 32768 + arow * D + ks * 32 + quad * 8);
      kvw.vl[ks] = *(const bf16x8*)(Wlo + 32768 + arow * D + ks * 32 + quad * 8);
    }
  }

  // ---- P3: double-buffered produce/consume over 4 j-tiles, 1 barrier each
  floatx4 att[2][8];
#pragma unroll
  for (int dt = 0; dt < 2; dt++)
#pragma unroll
    for (int qt = 0; qt < 8; qt++) att[dt][qt] = (floatx4){0.f, 0.f, 0.f, 0.f};
  float lsum[8] = {0.f, 0.f, 0.f, 0.f, 0.f, 0.f, 0.f, 0.f};
  const int permc = ((c16 >> 2) * 8) + (c16 & 3);

  unsigned short* kvb = (unsigned short*)(smem + 16384);  // 2 x 32KB
  kv_produce(xn, kvw, kvb, 0, h, hb, c16, quad);
  __syncthreads();
  for (int jt = 0; jt < 4; jt++) {
    if (jt < 3)
      kv_produce(xn, kvw, kvb + ((jt + 1) & 1) * 16384, jt + 1, h, hb, c16,
                 quad);
    attn_consume(kvb + (jt & 1) * 16384, h, c16, quad, permc, qf, att[0],
                 att[1], lsum);
    __syncthreads();
  }

  // ---- P4: normalize; deposit O as hi/lo PLANES; 1 barrier; project ----
#pragma unroll
  for (int qt = 0; qt < 8; qt++) {
    float l = lsum[qt];
    l += __shfl_xor(l, 16);
    l += __shfl_xor(l, 32);
    lsum[qt] = 1.0f / l;
  }

  unsigned short* Ohi = (unsigned short*)smem;          // [256][128] hi plane
  unsigned short* Olo = (unsigned short*)smem + 32768;  // [256][128] lo plane
#pragma unroll
  for (int t = 0; t < 8; t++) {
    const float inv = lsum[t];
    const int tokg = half * 128 + t * 16 + c16;
#pragma unroll
    for (int dt = 0; dt < 2; dt++) {
      floatx4 v4 = att[dt][t];
      const int d0 = h * 32 + dt * 16 + quad * 4;  // 4 consecutive dims
      ushort4 h4, l4;
      split_bf(v4[0] * inv, h4.x, l4.x);
      split_bf(v4[1] * inv, h4.y, l4.y);
      split_bf(v4[2] * inv, h4.z, l4.z);
      split_bf(v4[3] * inv, h4.w, l4.w);
      // XS only flips short-index bits 3..5, d0 is 4-aligned -> ushort4
      // stays inside one 16B granule; read side uses the same XS.
      *(ushort4*)&Ohi[tokg * 128 + XS(tokg, d0)] = h4;
      *(ushort4*)&Olo[tokg * 128 + XS(tokg, d0)] = l4;
    }
  }
  __syncthreads();

  // project: wave (g32, th) -> dims g32*32..+31, tokens th*128..+127
  const int g32 = w & 3;
  const int th = w >> 2;
  floatx4 oacc[2][8];
#pragma unroll
  for (int mi = 0; mi < 2; mi++)
#pragma unroll
    for (int nt = 0; nt < 8; nt++) oacc[mi][nt] = (floatx4){0.f, 0.f, 0.f, 0.f};
#pragma unroll
  for (int ks = 0; ks < 4; ks++) {
    bf16x8 wo_h[2], wo_l[2];
#pragma unroll
    for (int mi = 0; mi < 2; mi++) {
      const int m0 = g32 * 32 + mi * 16;
      wo_h[mi] = *(const bf16x8*)(Whi + 3 * 16384 + (m0 + c16) * D + ks * 32 + quad * 8);
      wo_l[mi] = *(const bf16x8*)(Wlo + 3 * 16384 + (m0 + c16) * D + ks * 32 + quad * 8);
    }
#pragma unroll
    for (int nt = 0; nt < 8; nt++) {
      const int tok = th * 128 + nt * 16 + c16;
      const int col = ks * 32 + quad * 8;  // 8 consecutive dims
      bf16x8 bh = *(const bf16x8*)&Ohi[tok * 128 + XS(tok, col)];
      bf16x8 bl = *(const bf16x8*)&Olo[tok * 128 + XS(tok, col)];
#pragma unroll
      for (int mi = 0; mi < 2; mi++) {
        oacc[mi][nt] = MF(wo_h[mi], bh, oacc[mi][nt]);
        oacc[mi][nt] = MF(wo_h[mi], bl, oacc[mi][nt]);
        oacc[mi][nt] = MF(wo_l[mi], bh, oacc[mi][nt]);
      }
    }
  }
#pragma unroll
  for (int nt = 0; nt < 8; nt++) {
    const int tok = th * 128 + nt * 16 + c16;
#pragma unroll
    for (int mi = 0; mi < 2; mi++) {
      float4 st4;
      st4.x = oacc[mi][nt][0];
      st4.y = oacc[mi][nt][1];
      st4.z = oacc[mi][nt][2];
      st4.w = oacc[mi][nt][3];
      *(float4*)(out + ((size_t)i * S + tok) * D + g32 * 32 + mi * 16 + quad * 4) = st4;
    }
  }
}

// ---------------------------------------------------------------------------
extern "C" void kernel_launch(void* const* d_in, const int* in_sizes, int n_in,
                              void* d_out, int out_size, void* d_ws,
                              size_t ws_size, hipStream_t stream) {
  const float* pair = (const float*)d_in[0];
  const float* ln_w = (const float*)d_in[1];
  const float* wq = (const float*)d_in[2];
  const float* wk = (const float*)d_in[3];
  const float* wv = (const float*)d_in[4];
  const float* wo = (const float*)d_in[5];
  float* out = (float*)d_out;

  unsigned short* Whi = (unsigned short*)d_ws;
  unsigned short* Wlo = Whi + 4 * 16384;

  wsplit_kernel<<<64, 256, 0, stream>>>(wq, wk, wv, wo, Whi, Wlo);
  fused_tri_kernel<<<S, 512, 0, stream>>>(pair, ln_w, Whi, Wlo, out);
}

// Round 9
// 140.854 us; speedup vs baseline: 1.1118x; 1.1118x over previous
//
#include <hip/hip_runtime.h>
#include <hip/hip_bf16.h>
#include <math.h>

#define S 256
#define D 128
#define H 4
#define HD 32

constexpr float EPS = 1e-5f;
constexpr float EXPC = 0.17677669529663687f * 1.44269504088896f;  // scale*log2(e)

typedef short bf16x8 __attribute__((ext_vector_type(8)));
typedef float floatx4 __attribute__((ext_vector_type(4)));

// R9: branchless RNE float->bf16. Bit-identical to __float2bfloat16 for all
// finite inputs (this kernel never produces NaN/inf); drops the header's
// NaN-guard VALU sequence (~6-8 ops -> 3-4 ops x ~900 calls/wave).
__device__ inline unsigned short f2bf_bits(float f) {
  unsigned int u = __float_as_uint(f);
  u += 0x7fffu + ((u >> 16) & 1u);
  return (unsigned short)(u >> 16);
}
__device__ inline short f2bf_s(float f) { return (short)f2bf_bits(f); }
__device__ inline float bfbits2f(unsigned short u) {
  union { float f; unsigned int i; } t;
  t.i = ((unsigned int)u) << 16;
  return t.f;
}
// split x into bf16 hi + bf16 lo with x ~= hi + lo (error <= 2^-18 relative)
__device__ inline void split_bf(float x, unsigned short& hi, unsigned short& lo) {
  hi = f2bf_bits(x);
  lo = f2bf_bits(x - bfbits2f(hi));
}
__device__ inline unsigned int pk2(float a, float b) {
  return (unsigned int)f2bf_bits(a) | ((unsigned int)f2bf_bits(b) << 16);
}

// ---------------------------------------------------------------------------
// K0: split the four 128x128 fp32 weights into bf16 hi/lo pairs, original
// [d][c] layout (== MFMA A-operand row layout). Order: q, k, v, o.
// ---------------------------------------------------------------------------
__global__ __launch_bounds__(256) void wsplit_kernel(
    const float* __restrict__ wq, const float* __restrict__ wk,
    const float* __restrict__ wv, const float* __restrict__ wo,
    unsigned short* __restrict__ whi, unsigned short* __restrict__ wlo) {
  int idx = blockIdx.x * 256 + threadIdx.x;  // 0..16383
  const float* srcs[4] = {wq, wk, wv, wo};
#pragma unroll
  for (int m = 0; m < 4; m++) {
    unsigned short hi, lo;
    split_bf(srcs[m][idx], hi, lo);
    whi[m * 16384 + idx] = hi;
    wlo[m * 16384 + idx] = lo;
  }
}

// ---------------------------------------------------------------------------
// R9 = R7 shell VERBATIM (8 waves / 512 thr / (512,2) / grid 256; 63us,
// session best) + hand-RNE f2bf only.
// R8 post-mortem: KVW hoist spilled — VGPR_Count pinned at 128 even at
// (512,2): the ARCH-VGPR half of the unified 256 budget is the binding
// cap (AGPR half holds accumulators). R7 sits exactly at 128 arch; any
// persistent arch liveness added (KVW 64 regs) -> scratch (FETCH 17.6->35,
// WRITE 32->67MB). Ledger: arch cap 128 — optimizations must be
// arch-reg-neutral. Hi/lo-plane P4 also reverted (conflicts 1.31->2.1M,
// confounded with spill; packed-Ost unpack is only ~1us anyway).
// Wave roles: (h=w>>1, half=w&1). P1: LN tokens w*32..+31. P2/consume:
// head h, queries half*128..+127. Produce: head h, hd-half half*16, all 64
// j-tokens, weights re-loaded per ks from L2 (arch-transient). P4: deposit
// own queries to packed Ost; project dims (w&3)*32..+31, tokens
// (w>>2)*128..+127 (full 128B-line stores).
// ---------------------------------------------------------------------------
#define XS(row, col) ((col) ^ (((row) & 7) << 3))

__device__ __forceinline__ floatx4 MF(bf16x8 a, bf16x8 b, floatx4 c) {
  return __builtin_amdgcn_mfma_f32_16x16x32_bf16(a, b, c, 0, 0, 0);
}

// produce K,V for tokens jt*64..+63, head h, hd hb..hb+15; fused mfma+store
__device__ __forceinline__ void kv_produce(
    const unsigned short* xn, const unsigned short* __restrict__ Whi,
    const unsigned short* __restrict__ Wlo, unsigned short* base, int jt,
    int h, int hb, int c16, int quad) {
  unsigned short* Kt = base;
  unsigned short* Vt = base + 8192;
  const unsigned short* wkh = Whi + 16384;
  const unsigned short* wkl = Wlo + 16384;
  const unsigned short* wvh = Whi + 32768;
  const unsigned short* wvl = Wlo + 32768;
  const int arow = h * 32 + hb + c16;
  floatx4 ak[4], av[4];
#pragma unroll
  for (int nt = 0; nt < 4; nt++) {
    ak[nt] = (floatx4){0.f, 0.f, 0.f, 0.f};
    av[nt] = (floatx4){0.f, 0.f, 0.f, 0.f};
  }
#pragma unroll
  for (int ks = 0; ks < 4; ks++) {
    bf16x8 bh[4];
#pragma unroll
    for (int nt = 0; nt < 4; nt++) {
      const int row = jt * 64 + nt * 16 + c16;
      bh[nt] = *(const bf16x8*)&xn[row * D + XS(row, ks * 32 + quad * 8)];
    }
    bf16x8 kh = *(const bf16x8*)(wkh + arow * D + ks * 32 + quad * 8);
    bf16x8 kl = *(const bf16x8*)(wkl + arow * D + ks * 32 + quad * 8);
    bf16x8 vh = *(const bf16x8*)(wvh + arow * D + ks * 32 + quad * 8);
    bf16x8 vl = *(const bf16x8*)(wvl + arow * D + ks * 32 + quad * 8);
#pragma unroll
    for (int nt = 0; nt < 4; nt++) {
      ak[nt] = MF(kh, bh[nt], ak[nt]);
      ak[nt] = MF(kl, bh[nt], ak[nt]);
      av[nt] = MF(vh, bh[nt], av[nt]);
      av[nt] = MF(vl, bh[nt], av[nt]);
    }
  }
  const int c2 = (hb >> 3) + (quad >> 1);
#pragma unroll
  for (int nt = 0; nt < 4; nt++) {
    const int jl = nt * 16 + c16;
    ushort4 pkk;
    pkk.x = f2bf_bits(ak[nt][0]);
    pkk.y = f2bf_bits(ak[nt][1]);
    pkk.z = f2bf_bits(ak[nt][2]);
    pkk.w = f2bf_bits(ak[nt][3]);
    *(ushort4*)(Kt + h * 2048 + c2 * 512 + jl * 8 + (quad & 1) * 4) = pkk;
#pragma unroll
    for (int r2 = 0; r2 < 4; r2++) {
      const int hd = hb + quad * 4 + r2;
      Vt[h * 2048 + hd * 64 + (((jl >> 3) ^ (hd & 7)) << 3) + (jl & 7)] =
          f2bf_bits(av[nt][r2]);
    }
  }
}

// consume one 64-token j-tile for this wave's 128 queries (head h)
__device__ __forceinline__ void attn_consume(const unsigned short* base, int h,
                                             int c16, int quad, int permc,
                                             const bf16x8 qf[8], floatx4 att0[8],
                                             floatx4 att1[8], float lsum[8]) {
  const unsigned short* Kt = base;
  const unsigned short* Vt = base + 8192;
#pragma unroll
  for (int jb = 0; jb < 2; jb++) {
    const int jbl = jb * 32;
    bf16x8 kf0 = *(const bf16x8*)(Kt + h * 2048 + quad * 512 + (jbl + permc) * 8);
    bf16x8 kf1 = *(const bf16x8*)(Kt + h * 2048 + quad * 512 + (jbl + permc + 4) * 8);
    const int ch = (jbl >> 3) + quad;
    bf16x8 vf0 = *(const bf16x8*)(Vt + h * 2048 + c16 * 64 + ((ch ^ (c16 & 7)) << 3));
    bf16x8 vf1 = *(const bf16x8*)(Vt + h * 2048 + (16 + c16) * 64 + ((ch ^ (c16 & 7)) << 3));
#pragma unroll
    for (int qt = 0; qt < 8; qt++) {
      floatx4 s0 = MF(kf0, qf[qt], (floatx4){0.f, 0.f, 0.f, 0.f});
      floatx4 s1 = MF(kf1, qf[qt], (floatx4){0.f, 0.f, 0.f, 0.f});
      float pr[8];
#pragma unroll
      for (int r = 0; r < 4; r++) pr[r] = exp2f(s0[r]);  // EXPC pre-folded in Q
#pragma unroll
      for (int r = 0; r < 4; r++) pr[4 + r] = exp2f(s1[r]);
      float ls = 0.f;
#pragma unroll
      for (int r = 0; r < 8; r++) ls += pr[r];
      lsum[qt] += ls;
      bf16x8 pf;
#pragma unroll
      for (int r = 0; r < 8; r++) pf[r] = f2bf_s(pr[r]);
      att0[qt] = MF(vf0, pf, att0[qt]);
      att1[qt] = MF(vf1, pf, att1[qt]);
    }
  }
}

__global__ __launch_bounds__(512, 2) void fused_tri_kernel(
    const float* __restrict__ pair, const float* __restrict__ ln_w,
    const unsigned short* __restrict__ Whi,
    const unsigned short* __restrict__ Wlo, float* __restrict__ out) {
  __shared__ unsigned int smem[32768];  // 128 KB
  unsigned short* xn = (unsigned short*)smem;  // [256][128] bf16, XS-swizzled

  const int i = blockIdx.x;
  const int w = (int)(threadIdx.x >> 6);  // 0..7
  const int lane = (int)(threadIdx.x & 63);
  const int c16 = lane & 15;
  const int quad = lane >> 4;
  const int h = w >> 1;     // head
  const int half = w & 1;   // query half / hd half
  const int hb = half * 16;

  // ---- P1: LayerNorm, 32 tokens/wave: prefetch ALL, then reduce ----
  {
    float4 w0 = *(const float4*)(ln_w + c16 * 8);
    float4 w1 = *(const float4*)(ln_w + c16 * 8 + 4);
    float4 xr0[8], xr1[8];
#pragma unroll
    for (int g = 0; g < 8; g++) {
      const int tok = w * 32 + g * 4 + quad;
      const float* src = pair + ((size_t)i * S + tok) * D + c16 * 8;
      xr0[g] = *(const float4*)(src);
      xr1[g] = *(const float4*)(src + 4);
    }
#pragma unroll
    for (int g = 0; g < 8; g++) {
      const int tok = w * 32 + g * 4 + quad;
      float4 x0 = xr0[g];
      float4 x1 = xr1[g];
      float s = (x0.x + x0.y) + (x0.z + x0.w) + (x1.x + x1.y) + (x1.z + x1.w);
      s += __shfl_xor(s, 1);
      s += __shfl_xor(s, 2);
      s += __shfl_xor(s, 4);
      s += __shfl_xor(s, 8);
      const float mu = s * (1.0f / D);
      float a[8];
      a[0] = x0.x - mu; a[1] = x0.y - mu; a[2] = x0.z - mu; a[3] = x0.w - mu;
      a[4] = x1.x - mu; a[5] = x1.y - mu; a[6] = x1.z - mu; a[7] = x1.w - mu;
      float vs = 0.f;
#pragma unroll
      for (int r = 0; r < 8; r++) vs = fmaf(a[r], a[r], vs);
      vs += __shfl_xor(vs, 1);
      vs += __shfl_xor(vs, 2);
      vs += __shfl_xor(vs, 4);
      vs += __shfl_xor(vs, 8);
      const float rinv = rsqrtf(vs * (1.0f / D) + EPS);
      const float wv8[8] = {w0.x, w0.y, w0.z, w0.w, w1.x, w1.y, w1.z, w1.w};
      unsigned int u[4];
#pragma unroll
      for (int r = 0; r < 4; r++) {
        unsigned int h0 = f2bf_bits(a[2 * r] * rinv * wv8[2 * r]);
        unsigned int h1 = f2bf_bits(a[2 * r + 1] * rinv * wv8[2 * r + 1]);
        u[r] = h0 | (h1 << 16);
      }
      uint4 st = {u[0], u[1], u[2], u[3]};
      *(uint4*)&xn[tok * D + XS(tok, c16 * 8)] = st;
    }
  }
  __syncthreads();

  // ---- P2: Q projection -> register fragments (128 queries/wave) ----
  bf16x8 qf[8];
  {
    bf16x8 qah[2][4], qal[2][4];
#pragma unroll
    for (int mi = 0; mi < 2; mi++)
#pragma unroll
      for (int ks = 0; ks < 4; ks++) {
        const int arow = h * 32 + mi * 16 + c16;
        qah[mi][ks] = *(const bf16x8*)(Whi + arow * D + ks * 32 + quad * 8);
        qal[mi][ks] = *(const bf16x8*)(Wlo + arow * D + ks * 32 + quad * 8);
      }
#pragma unroll
    for (int r = 0; r < 2; r++) {
      floatx4 acc[2][4];
#pragma unroll
      for (int mi = 0; mi < 2; mi++)
#pragma unroll
        for (int nt = 0; nt < 4; nt++) acc[mi][nt] = (floatx4){0.f, 0.f, 0.f, 0.f};
#pragma unroll
      for (int ks = 0; ks < 4; ks++) {
        bf16x8 bh[4];
#pragma unroll
        for (int nt = 0; nt < 4; nt++) {
          const int row = half * 128 + r * 64 + nt * 16 + c16;
          bh[nt] = *(const bf16x8*)&xn[row * D + XS(row, ks * 32 + quad * 8)];
        }
#pragma unroll
        for (int mi = 0; mi < 2; mi++)
#pragma unroll
          for (int nt = 0; nt < 4; nt++) {
            acc[mi][nt] = MF(qah[mi][ks], bh[nt], acc[mi][nt]);
            acc[mi][nt] = MF(qal[mi][ks], bh[nt], acc[mi][nt]);
          }
      }
      // quad redistribution: proj layout (4 consecutive d/lane) ->
      // attention B-fragment (8 consecutive hd/lane); EXPC folded here.
      const int srcL = c16 + (quad & 1) * 32;
      const int srcH = srcL + 16;
      const bool hi2 = quad >= 2;
#pragma unroll
      for (int nt = 0; nt < 4; nt++) {
        int pa = (int)pk2(acc[0][nt][0] * EXPC, acc[0][nt][1] * EXPC);
        int pb = (int)pk2(acc[0][nt][2] * EXPC, acc[0][nt][3] * EXPC);
        int pc = (int)pk2(acc[1][nt][0] * EXPC, acc[1][nt][1] * EXPC);
        int pd = (int)pk2(acc[1][nt][2] * EXPC, acc[1][nt][3] * EXPC);
        int aL = __shfl(pa, srcL), cL = __shfl(pc, srcL);
        int bL = __shfl(pb, srcL), dL = __shfl(pd, srcL);
        int aH = __shfl(pa, srcH), cH = __shfl(pc, srcH);
        int bH = __shfl(pb, srcH), dH = __shfl(pd, srcH);
        union { unsigned int u[4]; bf16x8 v; } qq_;
        qq_.u[0] = (unsigned int)(hi2 ? cL : aL);
        qq_.u[1] = (unsigned int)(hi2 ? dL : bL);
        qq_.u[2] = (unsigned int)(hi2 ? cH : aH);
        qq_.u[3] = (unsigned int)(hi2 ? dH : bH);
        qf[r * 4 + nt] = qq_.v;
      }
    }
  }

  // ---- P3: double-buffered produce/consume over 4 j-tiles, 1 barrier each
  floatx4 att[2][8];
#pragma unroll
  for (int dt = 0; dt < 2; dt++)
#pragma unroll
    for (int qt = 0; qt < 8; qt++) att[dt][qt] = (floatx4){0.f, 0.f, 0.f, 0.f};
  float lsum[8] = {0.f, 0.f, 0.f, 0.f, 0.f, 0.f, 0.f, 0.f};
  const int permc = ((c16 >> 2) * 8) + (c16 & 3);

  unsigned short* kvb = (unsigned short*)(smem + 16384);  // 2 x 32KB
  kv_produce(xn, Whi, Wlo, kvb, 0, h, hb, c16, quad);
  __syncthreads();
  for (int jt = 0; jt < 4; jt++) {
    if (jt < 3)
      kv_produce(xn, Whi, Wlo, kvb + ((jt + 1) & 1) * 16384, jt + 1, h, hb,
                 c16, quad);
    attn_consume(kvb + (jt & 1) * 16384, h, c16, quad, permc, qf, att[0],
                 att[1], lsum);
    __syncthreads();
  }

  // ---- P4: normalize; deposit ALL O into 128KB overlay; 1 barrier; proj
#pragma unroll
  for (int qt = 0; qt < 8; qt++) {
    float l = lsum[qt];
    l += __shfl_xor(l, 16);
    l += __shfl_xor(l, 32);
    lsum[qt] = 1.0f / l;
  }

  unsigned int* Ost = smem;  // [256 tok][128 d] packed hi|lo<<16 (xn+kv dead)
#pragma unroll
  for (int t = 0; t < 8; t++) {
    const float inv = lsum[t];
    const int tokg = half * 128 + t * 16 + c16;
#pragma unroll
    for (int dt = 0; dt < 2; dt++) {
      floatx4 v4 = att[dt][t];
      unsigned int u[4];
      unsigned short hh, ll;
      split_bf(v4[0] * inv, hh, ll); u[0] = (unsigned)hh | ((unsigned)ll << 16);
      split_bf(v4[1] * inv, hh, ll); u[1] = (unsigned)hh | ((unsigned)ll << 16);
      split_bf(v4[2] * inv, hh, ll); u[2] = (unsigned)hh | ((unsigned)ll << 16);
      split_bf(v4[3] * inv, hh, ll); u[3] = (unsigned)hh | ((unsigned)ll << 16);
      const int chunk = h * 8 + dt * 4 + quad;
      uint4 st = {u[0], u[1], u[2], u[3]};
      *(uint4*)(Ost + tokg * 128 + ((chunk ^ c16) << 2)) = st;
    }
  }
  __syncthreads();

  // project: wave (g32, th) -> dims g32*32..+31, tokens th*128..+127
  const int g32 = w & 3;
  const int th = w >> 2;
  floatx4 oacc[2][8];
#pragma unroll
  for (int mi = 0; mi < 2; mi++)
#pragma unroll
    for (int nt = 0; nt < 8; nt++) oacc[mi][nt] = (floatx4){0.f, 0.f, 0.f, 0.f};
#pragma unroll
  for (int ks = 0; ks < 4; ks++) {
    bf16x8 wo_h[2], wo_l[2];
#pragma unroll
    for (int mi = 0; mi < 2; mi++) {
      const int m0 = g32 * 32 + mi * 16;
      wo_h[mi] = *(const bf16x8*)(Whi + 3 * 16384 + (m0 + c16) * D + ks * 32 + quad * 8);
      wo_l[mi] = *(const bf16x8*)(Wlo + 3 * 16384 + (m0 + c16) * D + ks * 32 + quad * 8);
    }
#pragma unroll
    for (int nt = 0; nt < 8; nt++) {
      const int tok = th * 128 + nt * 16 + c16;
      const int ch0 = ks * 8 + quad * 2;
      uint4 u0 = *(const uint4*)(Ost + tok * 128 + ((ch0 ^ c16) << 2));
      uint4 u1 = *(const uint4*)(Ost + tok * 128 + (((ch0 + 1) ^ c16) << 2));
      unsigned int bhw[4], blw[4];
      bhw[0] = (u0.x & 0xFFFFu) | (u0.y << 16);
      blw[0] = (u0.x >> 16) | (u0.y & 0xFFFF0000u);
      bhw[1] = (u0.z & 0xFFFFu) | (u0.w << 16);
      blw[1] = (u0.z >> 16) | (u0.w & 0xFFFF0000u);
      bhw[2] = (u1.x & 0xFFFFu) | (u1.y << 16);
      blw[2] = (u1.x >> 16) | (u1.y & 0xFFFF0000u);
      bhw[3] = (u1.z & 0xFFFFu) | (u1.w << 16);
      blw[3] = (u1.z >> 16) | (u1.w & 0xFFFF0000u);
      bf16x8 bh = *(bf16x8*)bhw;
      bf16x8 bl = *(bf16x8*)blw;
#pragma unroll
      for (int mi = 0; mi < 2; mi++) {
        oacc[mi][nt] = MF(wo_h[mi], bh, oacc[mi][nt]);
        oacc[mi][nt] = MF(wo_h[mi], bl, oacc[mi][nt]);
        oacc[mi][nt] = MF(wo_l[mi], bh, oacc[mi][nt]);
      }
    }
  }
#pragma unroll
  for (int nt = 0; nt < 8; nt++) {
    const int tok = th * 128 + nt * 16 + c16;
#pragma unroll
    for (int mi = 0; mi < 2; mi++) {
      float4 st4;
      st4.x = oacc[mi][nt][0];
      st4.y = oacc[mi][nt][1];
      st4.z = oacc[mi][nt][2];
      st4.w = oacc[mi][nt][3];
      *(float4*)(out + ((size_t)i * S + tok) * D + g32 * 32 + mi * 16 + quad * 4) = st4;
    }
  }
}

// ---------------------------------------------------------------------------
extern "C" void kernel_launch(void* const* d_in, const int* in_sizes, int n_in,
                              void* d_out, int out_size, void* d_ws,
                              size_t ws_size, hipStream_t stream) {
  const float* pair = (const float*)d_in[0];
  const float* ln_w = (const float*)d_in[1];
  const float* wq = (const float*)d_in[2];
  const float* wk = (const float*)d_in[3];
  const float* wv = (const float*)d_in[4];
  const float* wo = (const float*)d_in[5];
  float* out = (float*)d_out;

  unsigned short* Whi = (unsigned short*)d_ws;
  unsigned short* Wlo = Whi + 4 * 16384;

  wsplit_kernel<<<64, 256, 0, stream>>>(wq, wk, wv, wo, Whi, Wlo);
  fused_tri_kernel<<<S, 512, 0, stream>>>(pair, ln_w, Whi, Wlo, out);
}

// Round 10
// 135.615 us; speedup vs baseline: 1.1547x; 1.0386x over previous
//
#include <hip/hip_runtime.h>
#include <hip/hip_bf16.h>
#include <math.h>

#define S 256
#define D 128
#define H 4
#define HD 32

constexpr float EPS = 1e-5f;
constexpr float EXPC = 0.17677669529663687f * 1.44269504088896f;  // scale*log2(e)

typedef short bf16x8 __attribute__((ext_vector_type(8)));
typedef float floatx4 __attribute__((ext_vector_type(4)));

// R10: builtin f2bf RESTORED. R9 post-mortem: hand-RNE added ~2K VALU
// instrs/wave (VALUBusy 35->40, dur 63->67) — hipcc lowers
// __float2bfloat16 to the HW cvt(_pk) path; never hand-write it (m240).
union BfBits { __hip_bfloat16 b; unsigned short u; };
__device__ inline unsigned short f2bf_bits(float f) {
  BfBits t;
  t.b = __float2bfloat16(f);
  return t.u;
}
__device__ inline short f2bf_s(float f) { return (short)f2bf_bits(f); }
__device__ inline float bfbits2f(unsigned short u) {
  union { float f; unsigned int i; } t;
  t.i = ((unsigned int)u) << 16;
  return t.f;
}
// split x into bf16 hi + bf16 lo with x ~= hi + lo (error <= 2^-18 relative)
__device__ inline void split_bf(float x, unsigned short& hi, unsigned short& lo) {
  hi = f2bf_bits(x);
  lo = f2bf_bits(x - bfbits2f(hi));
}
__device__ inline unsigned int pk2(float a, float b) {
  return (unsigned int)f2bf_bits(a) | ((unsigned int)f2bf_bits(b) << 16);
}

// ---------------------------------------------------------------------------
// K0: split the four 128x128 fp32 weights into bf16 hi/lo pairs, original
// [d][c] layout (== MFMA A-operand row layout). Order: q, k, v, o.
// ---------------------------------------------------------------------------
__global__ __launch_bounds__(256) void wsplit_kernel(
    const float* __restrict__ wq, const float* __restrict__ wk,
    const float* __restrict__ wv, const float* __restrict__ wo,
    unsigned short* __restrict__ whi, unsigned short* __restrict__ wlo) {
  int idx = blockIdx.x * 256 + threadIdx.x;  // 0..16383
  const float* srcs[4] = {wq, wk, wv, wo};
#pragma unroll
  for (int m = 0; m < 4; m++) {
    unsigned short hi, lo;
    split_bf(srcs[m][idx], hi, lo);
    whi[m * 16384 + idx] = hi;
    wlo[m * 16384 + idx] = lo;
  }
}

// ---------------------------------------------------------------------------
// R16 = R7 shell (8 waves / 512 thr / (512,2) / grid 256 — the spill-free
// shape; arch-VGPR cap 128, reg-neutral changes only) + two VALU/LDS cuts,
// both bit-identical in output:
//  1. V^T produce: av = MF(bh, vw) (operand swap; same weight bytes in the
//     B role, same k-order products -> bit-identical). Each lane then holds
//     4 consecutive j at fixed hd: the 16 scalar V ds_write_b16 per tile
//     become 4 ushort4 writes into the SAME swizzled Vt layout.
//  2. Plane Ost: O deposited as separate hi/lo planes (64KB+64KB overlay,
//     granule swizzle gran^=(tok&7), bank-checked ~2-way both sides).
//     Projection reads become direct bf16x8 loads: -512 unpack-VALU/wave.
//     (R8's version failed on a bad layout + spill confound; this one is
//     reg-neutral and derived from the working packed-Ost swizzle.)
// Wave roles: (h=w>>1, half=w&1). P1: LN tokens w*32..+31. P2/consume:
// head h, queries half*128..+127. Produce: head h, hd-half half*16, all 64
// j-tokens, weights re-loaded per ks from L2 (arch-transient). P4: deposit
// own queries to hi/lo planes; project dims (w&3)*32..+31, tokens
// (w>>2)*128..+127 (full 128B-line stores).
// ---------------------------------------------------------------------------
#define XS(row, col) ((col) ^ (((row) & 7) << 3))

__device__ __forceinline__ floatx4 MF(bf16x8 a, bf16x8 b, floatx4 c) {
  return __builtin_amdgcn_mfma_f32_16x16x32_bf16(a, b, c, 0, 0, 0);
}

// produce K,V for tokens jt*64..+63, head h, hd hb..hb+15; fused mfma+store
__device__ __forceinline__ void kv_produce(
    const unsigned short* xn, const unsigned short* __restrict__ Whi,
    const unsigned short* __restrict__ Wlo, unsigned short* base, int jt,
    int h, int hb, int c16, int quad) {
  unsigned short* Kt = base;
  unsigned short* Vt = base + 8192;
  const unsigned short* wkh = Whi + 16384;
  const unsigned short* wkl = Wlo + 16384;
  const unsigned short* wvh = Whi + 32768;
  const unsigned short* wvl = Wlo + 32768;
  const int arow = h * 32 + hb + c16;
  floatx4 ak[4], av[4];
#pragma unroll
  for (int nt = 0; nt < 4; nt++) {
    ak[nt] = (floatx4){0.f, 0.f, 0.f, 0.f};
    av[nt] = (floatx4){0.f, 0.f, 0.f, 0.f};
  }
#pragma unroll
  for (int ks = 0; ks < 4; ks++) {
    bf16x8 bh[4];
#pragma unroll
    for (int nt = 0; nt < 4; nt++) {
      const int row = jt * 64 + nt * 16 + c16;
      bh[nt] = *(const bf16x8*)&xn[row * D + XS(row, ks * 32 + quad * 8)];
    }
    bf16x8 kh = *(const bf16x8*)(wkh + arow * D + ks * 32 + quad * 8);
    bf16x8 kl = *(const bf16x8*)(wkl + arow * D + ks * 32 + quad * 8);
    bf16x8 vh = *(const bf16x8*)(wvh + arow * D + ks * 32 + quad * 8);
    bf16x8 vl = *(const bf16x8*)(wvl + arow * D + ks * 32 + quad * 8);
#pragma unroll
    for (int nt = 0; nt < 4; nt++) {
      ak[nt] = MF(kh, bh[nt], ak[nt]);
      ak[nt] = MF(kl, bh[nt], ak[nt]);
      // V^T: bh as A, weights as B -> av[nt][r] = V[j=nt*16+quad*4+r][hd=hb+c16]
      av[nt] = MF(bh[nt], vh, av[nt]);
      av[nt] = MF(bh[nt], vl, av[nt]);
    }
  }
  const int c2 = (hb >> 3) + (quad >> 1);
#pragma unroll
  for (int nt = 0; nt < 4; nt++) {
    const int jl = nt * 16 + c16;
    ushort4 pkk;
    pkk.x = f2bf_bits(ak[nt][0]);
    pkk.y = f2bf_bits(ak[nt][1]);
    pkk.z = f2bf_bits(ak[nt][2]);
    pkk.w = f2bf_bits(ak[nt][3]);
    *(ushort4*)(Kt + h * 2048 + c2 * 512 + jl * 8 + (quad & 1) * 4) = pkk;
    // V store: 4 consecutive j at fixed hd=hb+c16, same swizzled Vt layout
    // element [hd][j] @ hd*64 + ((j>>3)^(hd&7))*8 + (j&7); here j>>3 =
    // nt*2+(quad>>1), j&7 = (quad&1)*4 + r, (hb+c16)&7 = c16&7.
    ushort4 pv;
    pv.x = f2bf_bits(av[nt][0]);
    pv.y = f2bf_bits(av[nt][1]);
    pv.z = f2bf_bits(av[nt][2]);
    pv.w = f2bf_bits(av[nt][3]);
    *(ushort4*)(Vt + h * 2048 + (hb + c16) * 64 +
                (((nt * 2 + (quad >> 1)) ^ (c16 & 7)) << 3) + (quad & 1) * 4) =
        pv;
  }
}

// consume one 64-token j-tile for this wave's 128 queries (head h)
__device__ __forceinline__ void attn_consume(const unsigned short* base, int h,
                                             int c16, int quad, int permc,
                                             const bf16x8 qf[8], floatx4 att0[8],
                                             floatx4 att1[8], float lsum[8]) {
  const unsigned short* Kt = base;
  const unsigned short* Vt = base + 8192;
#pragma unroll
  for (int jb = 0; jb < 2; jb++) {
    const int jbl = jb * 32;
    bf16x8 kf0 = *(const bf16x8*)(Kt + h * 2048 + quad * 512 + (jbl + permc) * 8);
    bf16x8 kf1 = *(const bf16x8*)(Kt + h * 2048 + quad * 512 + (jbl + permc + 4) * 8);
    const int ch = (jbl >> 3) + quad;
    bf16x8 vf0 = *(const bf16x8*)(Vt + h * 2048 + c16 * 64 + ((ch ^ (c16 & 7)) << 3));
    bf16x8 vf1 = *(const bf16x8*)(Vt + h * 2048 + (16 + c16) * 64 + ((ch ^ (c16 & 7)) << 3));
#pragma unroll
    for (int qt = 0; qt < 8; qt++) {
      floatx4 s0 = MF(kf0, qf[qt], (floatx4){0.f, 0.f, 0.f, 0.f});
      floatx4 s1 = MF(kf1, qf[qt], (floatx4){0.f, 0.f, 0.f, 0.f});
      float pr[8];
#pragma unroll
      for (int r = 0; r < 4; r++) pr[r] = exp2f(s0[r]);  // EXPC pre-folded in Q
#pragma unroll
      for (int r = 0; r < 4; r++) pr[4 + r] = exp2f(s1[r]);
      float ls = 0.f;
#pragma unroll
      for (int r = 0; r < 8; r++) ls += pr[r];
      lsum[qt] += ls;
      bf16x8 pf;
#pragma unroll
      for (int r = 0; r < 8; r++) pf[r] = f2bf_s(pr[r]);
      att0[qt] = MF(vf0, pf, att0[qt]);
      att1[qt] = MF(vf1, pf, att1[qt]);
    }
  }
}

__global__ __launch_bounds__(512, 2) void fused_tri_kernel(
    const float* __restrict__ pair, const float* __restrict__ ln_w,
    const unsigned short* __restrict__ Whi,
    const unsigned short* __restrict__ Wlo, float* __restrict__ out) {
  __shared__ unsigned int smem[32768];  // 128 KB
  unsigned short* xn = (unsigned short*)smem;  // [256][128] bf16, XS-swizzled

  const int i = blockIdx.x;
  const int w = (int)(threadIdx.x >> 6);  // 0..7
  const int lane = (int)(threadIdx.x & 63);
  const int c16 = lane & 15;
  const int quad = lane >> 4;
  const int h = w >> 1;     // head
  const int half = w & 1;   // query half / hd half
  const int hb = half * 16;

  // ---- P1: LayerNorm, 32 tokens/wave: prefetch ALL, then reduce ----
  {
    float4 w0 = *(const float4*)(ln_w + c16 * 8);
    float4 w1 = *(const float4*)(ln_w + c16 * 8 + 4);
    float4 xr0[8], xr1[8];
#pragma unroll
    for (int g = 0; g < 8; g++) {
      const int tok = w * 32 + g * 4 + quad;
      const float* src = pair + ((size_t)i * S + tok) * D + c16 * 8;
      xr0[g] = *(const float4*)(src);
      xr1[g] = *(const float4*)(src + 4);
    }
#pragma unroll
    for (int g = 0; g < 8; g++) {
      const int tok = w * 32 + g * 4 + quad;
      float4 x0 = xr0[g];
      float4 x1 = xr1[g];
      float s = (x0.x + x0.y) + (x0.z + x0.w) + (x1.x + x1.y) + (x1.z + x1.w);
      s += __shfl_xor(s, 1);
      s += __shfl_xor(s, 2);
      s += __shfl_xor(s, 4);
      s += __shfl_xor(s, 8);
      const float mu = s * (1.0f / D);
      float a[8];
      a[0] = x0.x - mu; a[1] = x0.y - mu; a[2] = x0.z - mu; a[3] = x0.w - mu;
      a[4] = x1.x - mu; a[5] = x1.y - mu; a[6] = x1.z - mu; a[7] = x1.w - mu;
      float vs = 0.f;
#pragma unroll
      for (int r = 0; r < 8; r++) vs = fmaf(a[r], a[r], vs);
      vs += __shfl_xor(vs, 1);
      vs += __shfl_xor(vs, 2);
      vs += __shfl_xor(vs, 4);
      vs += __shfl_xor(vs, 8);
      const float rinv = rsqrtf(vs * (1.0f / D) + EPS);
      const float wv8[8] = {w0.x, w0.y, w0.z, w0.w, w1.x, w1.y, w1.z, w1.w};
      unsigned int u[4];
#pragma unroll
      for (int r = 0; r < 4; r++) {
        unsigned int h0 = f2bf_bits(a[2 * r] * rinv * wv8[2 * r]);
        unsigned int h1 = f2bf_bits(a[2 * r + 1] * rinv * wv8[2 * r + 1]);
        u[r] = h0 | (h1 << 16);
      }
      uint4 st = {u[0], u[1], u[2], u[3]};
      *(uint4*)&xn[tok * D + XS(tok, c16 * 8)] = st;
    }
  }
  __syncthreads();

  // ---- P2: Q projection -> register fragments (128 queries/wave) ----
  bf16x8 qf[8];
  {
    bf16x8 qah[2][4], qal[2][4];
#pragma unroll
    for (int mi = 0; mi < 2; mi++)
#pragma unroll
      for (int ks = 0; ks < 4; ks++) {
        const int arow = h * 32 + mi * 16 + c16;
        qah[mi][ks] = *(const bf16x8*)(Whi + arow * D + ks * 32 + quad * 8);
        qal[mi][ks] = *(const bf16x8*)(Wlo + arow * D + ks * 32 + quad * 8);
      }
#pragma unroll
    for (int r = 0; r < 2; r++) {
      floatx4 acc[2][4];
#pragma unroll
      for (int mi = 0; mi < 2; mi++)
#pragma unroll
        for (int nt = 0; nt < 4; nt++) acc[mi][nt] = (floatx4){0.f, 0.f, 0.f, 0.f};
#pragma unroll
      for (int ks = 0; ks < 4; ks++) {
        bf16x8 bh[4];
#pragma unroll
        for (int nt = 0; nt < 4; nt++) {
          const int row = half * 128 + r * 64 + nt * 16 + c16;
          bh[nt] = *(const bf16x8*)&xn[row * D + XS(row, ks * 32 + quad * 8)];
        }
#pragma unroll
        for (int mi = 0; mi < 2; mi++)
#pragma unroll
          for (int nt = 0; nt < 4; nt++) {
            acc[mi][nt] = MF(qah[mi][ks], bh[nt], acc[mi][nt]);
            acc[mi][nt] = MF(qal[mi][ks], bh[nt], acc[mi][nt]);
          }
      }
      // quad redistribution: proj layout (4 consecutive d/lane) ->
      // attention B-fragment (8 consecutive hd/lane); EXPC folded here.
      const int srcL = c16 + (quad & 1) * 32;
      const int srcH = srcL + 16;
      const bool hi2 = quad >= 2;
#pragma unroll
      for (int nt = 0; nt < 4; nt++) {
        int pa = (int)pk2(acc[0][nt][0] * EXPC, acc[0][nt][1] * EXPC);
        int pb = (int)pk2(acc[0][nt][2] * EXPC, acc[0][nt][3] * EXPC);
        int pc = (int)pk2(acc[1][nt][0] * EXPC, acc[1][nt][1] * EXPC);
        int pd = (int)pk2(acc[1][nt][2] * EXPC, acc[1][nt][3] * EXPC);
        int aL = __shfl(pa, srcL), cL = __shfl(pc, srcL);
        int bL = __shfl(pb, srcL), dL = __shfl(pd, srcL);
        int aH = __shfl(pa, srcH), cH = __shfl(pc, srcH);
        int bH = __shfl(pb, srcH), dH = __shfl(pd, srcH);
        union { unsigned int u[4]; bf16x8 v; } qq_;
        qq_.u[0] = (unsigned int)(hi2 ? cL : aL);
        qq_.u[1] = (unsigned int)(hi2 ? dL : bL);
        qq_.u[2] = (unsigned int)(hi2 ? cH : aH);
        qq_.u[3] = (unsigned int)(hi2 ? dH : bH);
        qf[r * 4 + nt] = qq_.v;
      }
    }
  }

  // ---- P3: double-buffered produce/consume over 4 j-tiles, 1 barrier each
  floatx4 att[2][8];
#pragma unroll
  for (int dt = 0; dt < 2; dt++)
#pragma unroll
    for (int qt = 0; qt < 8; qt++) att[dt][qt] = (floatx4){0.f, 0.f, 0.f, 0.f};
  float lsum[8] = {0.f, 0.f, 0.f, 0.f, 0.f, 0.f, 0.f, 0.f};
  const int permc = ((c16 >> 2) * 8) + (c16 & 3);

  unsigned short* kvb = (unsigned short*)(smem + 16384);  // 2 x 32KB
  kv_produce(xn, Whi, Wlo, kvb, 0, h, hb, c16, quad);
  __syncthreads();
  for (int jt = 0; jt < 4; jt++) {
    if (jt < 3)
      kv_produce(xn, Whi, Wlo, kvb + ((jt + 1) & 1) * 16384, jt + 1, h, hb,
                 c16, quad);
    attn_consume(kvb + (jt & 1) * 16384, h, c16, quad, permc, qf, att[0],
                 att[1], lsum);
    __syncthreads();
  }

  // ---- P4: normalize; deposit O as hi/lo planes; 1 barrier; project ----
#pragma unroll
  for (int qt = 0; qt < 8; qt++) {
    float l = lsum[qt];
    l += __shfl_xor(l, 16);
    l += __shfl_xor(l, 32);
    lsum[qt] = 1.0f / l;
  }

  // Plane layout: element [tok][d] @ tok*128 + ((d>>3) ^ (tok&7))*8 + (d&7)
  unsigned short* Ohi = (unsigned short*)smem;          // [256][128] hi plane
  unsigned short* Olo = (unsigned short*)smem + 32768;  // [256][128] lo plane
#pragma unroll
  for (int t = 0; t < 8; t++) {
    const float inv = lsum[t];
    const int tokg = half * 128 + t * 16 + c16;
#pragma unroll
    for (int dt = 0; dt < 2; dt++) {
      floatx4 v4 = att[dt][t];
      // dims d0 = h*32 + dt*16 + quad*4 .. +3 -> gran = h*4+dt*2+(quad>>1)
      const int gran = h * 4 + dt * 2 + (quad >> 1);
      const int addr = tokg * 128 + ((gran ^ (tokg & 7)) << 3) + (quad & 1) * 4;
      ushort4 h4, l4;
      split_bf(v4[0] * inv, h4.x, l4.x);
      split_bf(v4[1] * inv, h4.y, l4.y);
      split_bf(v4[2] * inv, h4.z, l4.z);
      split_bf(v4[3] * inv, h4.w, l4.w);
      *(ushort4*)&Ohi[addr] = h4;
      *(ushort4*)&Olo[addr] = l4;
    }
  }
  __syncthreads();

  // project: wave (g32, th) -> dims g32*32..+31, tokens th*128..+127
  const int g32 = w & 3;
  const int th = w >> 2;
  floatx4 oacc[2][8];
#pragma unroll
  for (int mi = 0; mi < 2; mi++)
#pragma unroll
    for (int nt = 0; nt < 8; nt++) oacc[mi][nt] = (floatx4){0.f, 0.f, 0.f, 0.f};
#pragma unroll
  for (int ks = 0; ks < 4; ks++) {
    bf16x8 wo_h[2], wo_l[2];
#pragma unroll
    for (int mi = 0; mi < 2; mi++) {
      const int m0 = g32 * 32 + mi * 16;
      wo_h[mi] = *(const bf16x8*)(Whi + 3 * 16384 + (m0 + c16) * D + ks * 32 + quad * 8);
      wo_l[mi] = *(const bf16x8*)(Wlo + 3 * 16384 + (m0 + c16) * D + ks * 32 + quad * 8);
    }
#pragma unroll
    for (int nt = 0; nt < 8; nt++) {
      const int tok = th * 128 + nt * 16 + c16;
      const int gran = ks * 4 + quad;  // dims ks*32+quad*8 .. +7
      const int addr = tok * 128 + ((gran ^ (tok & 7)) << 3);
      bf16x8 bh = *(const bf16x8*)&Ohi[addr];
      bf16x8 bl = *(const bf16x8*)&Olo[addr];
#pragma unroll
      for (int mi = 0; mi < 2; mi++) {
        oacc[mi][nt] = MF(wo_h[mi], bh, oacc[mi][nt]);
        oacc[mi][nt] = MF(wo_h[mi], bl, oacc[mi][nt]);
        oacc[mi][nt] = MF(wo_l[mi], bh, oacc[mi][nt]);
      }
    }
  }
#pragma unroll
  for (int nt = 0; nt < 8; nt++) {
    const int tok = th * 128 + nt * 16 + c16;
#pragma unroll
    for (int mi = 0; mi < 2; mi++) {
      float4 st4;
      st4.x = oacc[mi][nt][0];
      st4.y = oacc[mi][nt][1];
      st4.z = oacc[mi][nt][2];
      st4.w = oacc[mi][nt][3];
      *(float4*)(out + ((size_t)i * S + tok) * D + g32 * 32 + mi * 16 + quad * 4) = st4;
    }
  }
}

// ---------------------------------------------------------------------------
extern "C" void kernel_launch(void* const* d_in, const int* in_sizes, int n_in,
                              void* d_out, int out_size, void* d_ws,
                              size_t ws_size, hipStream_t stream) {
  const float* pair = (const float*)d_in[0];
  const float* ln_w = (const float*)d_in[1];
  const float* wq = (const float*)d_in[2];
  const float* wk = (const float*)d_in[3];
  const float* wv = (const float*)d_in[4];
  const float* wo = (const float*)d_in[5];
  float* out = (float*)d_out;

  unsigned short* Whi = (unsigned short*)d_ws;
  unsigned short* Wlo = Whi + 4 * 16384;

  wsplit_kernel<<<64, 256, 0, stream>>>(wq, wk, wv, wo, Whi, Wlo);
  fused_tri_kernel<<<S, 512, 0, stream>>>(pair, ln_w, Whi, Wlo, out);
}